// Round 4
// baseline (236.158 us; speedup 1.0000x reference)
//
#include <hip/hip_runtime.h>

// Batched autocorrelation, X:[4096,8192] f32 -> out:[4096,64] f32.
// Per-row correlation as bf16 MFMA Gram matrices:
//   X_i[m] = x[32 i + m];  G_d[m][n] = sum_i X_i[m] * X_{i+d}[n], d=0..2
//   R_{32q+s} = sum_{m+s<32} G_q[m][m+s] + sum_{m+s>=32} G_{q+1}[m][m+s-32]
// Centering folded in algebraically (fp32):
//   C_k = R_k - mu*(2S - P_k - Q_k) + (T-k) mu^2 ;  out = C_k / C_0
//
// R4 = R3 kernel, launched 3x (idempotent) as a TIMING EXPERIMENT:
// bench dur_us = harness_overhead + 3*X  =>  X = (dur - 188.1)/2.
// The kernel is invisible in rocprof (all top-5 dispatches are 78 us
// harness poison-fills), so this is the only way to measure X and decide
// whether headroom remains. Kernel body is byte-identical to R3 (passed,
// absmax 2.44e-4).

typedef __bf16 bf16x8 __attribute__((ext_vector_type(8)));
typedef float f32x16 __attribute__((ext_vector_type(16)));
typedef unsigned int uint32;

#define T_LEN 8192
#define WPB 4                       // waves (rows) per block
#define GB_STRIDE 34                // shorts per G row (+2 pad)
#define GB_SHORTS (96 * GB_STRIDE)  // 3 matrices x 32 rows = 6528 B / wave

__device__ __forceinline__ uint32 pack2bf(float a, float b) { // (lo=a, hi=b) RNE
  uint32 ua = __builtin_bit_cast(uint32, a);
  uint32 ub = __builtin_bit_cast(uint32, b);
  ua += 0x7fffu + ((ua >> 16) & 1u);
  ub += 0x7fffu + ((ub >> 16) & 1u);
  return (ua >> 16) | (ub & 0xffff0000u);
}
__device__ __forceinline__ short f2bf(float f) {
  uint32 u = __builtin_bit_cast(uint32, f);
  return (short)((u + 0x7fffu + ((u >> 16) & 1u)) >> 16);
}
__device__ __forceinline__ float bf2f(short h) {
  uint32 u = ((uint32)(unsigned short)h) << 16;
  return __builtin_bit_cast(float, u);
}

__global__ __launch_bounds__(WPB * 64, 4)
void autocorr_kernel(const float* __restrict__ X, float* __restrict__ out, int nrows) {
  __shared__ short gb_all[WPB * GB_SHORTS];
  const int wave = threadIdx.x >> 6;
  const int lane = threadIdx.x & 63;
  const int row = blockIdx.x * WPB + wave;
  if (row >= nrows) return;               // no barriers anywhere: waves independent
  short* gb = gb_all + wave * GB_SHORTS;

  const int m = lane & 31;                // A-role row m / B-role col n
  const int sh = lane >> 5;               // K-half s
  const float* __restrict__ base = X + (size_t)row * T_LEN + (sh << 8) + m;

  f32x16 g0 = {}, g1 = {}, g2 = {};
  float ssum = 0.f;

#define CHUNK_BODY(PP, E8, E9)                                                  \
  {                                                                             \
    float e0 = (PP)[0],   e1 = (PP)[32],  e2 = (PP)[64],  e3 = (PP)[96];        \
    float e4 = (PP)[128], e5 = (PP)[160], e6 = (PP)[192], e7 = (PP)[224];       \
    float e8 = (E8), e9 = (E9);                                                 \
    ssum += ((e0 + e1) + (e2 + e3)) + ((e4 + e5) + (e6 + e7));                  \
    uint32 u0 = pack2bf(e0, e1), u1 = pack2bf(e2, e3), u2 = pack2bf(e4, e5);    \
    uint32 u3 = pack2bf(e6, e7), u4 = pack2bf(e8, e9);                          \
    int4 a4 = make_int4((int)u0, (int)u1, (int)u2, (int)u3);                    \
    int4 b1;                                                                    \
    b1.x = (int)((u0 >> 16) | (u1 << 16));                                      \
    b1.y = (int)((u1 >> 16) | (u2 << 16));                                      \
    b1.z = (int)((u2 >> 16) | (u3 << 16));                                      \
    b1.w = (int)((u3 >> 16) | (u4 << 16));                                      \
    int4 b2 = make_int4((int)u1, (int)u2, (int)u3, (int)u4);                    \
    bf16x8 fa = __builtin_bit_cast(bf16x8, a4);                                 \
    bf16x8 f1 = __builtin_bit_cast(bf16x8, b1);                                 \
    bf16x8 f2 = __builtin_bit_cast(bf16x8, b2);                                 \
    g0 = __builtin_amdgcn_mfma_f32_32x32x16_bf16(fa, fa, g0, 0, 0, 0);          \
    g1 = __builtin_amdgcn_mfma_f32_32x32x16_bf16(fa, f1, g1, 0, 0, 0);          \
    g2 = __builtin_amdgcn_mfma_f32_32x32x16_bf16(fa, f2, g2, 0, 0, 0);          \
  }

#pragma unroll 3
  for (int c = 0; c < 15; ++c) {
    const float* p = base + (c << 9);
    CHUNK_BODY(p, p[256], p[288])
  }
  { // last chunk: spill elements for the upper half are past end of row -> 0
    const float* p = base + (15 << 9);
    float e8s = 0.f, e9s = 0.f;
    if (!sh) { e8s = p[256]; e9s = p[288]; }   // exec-masked loads, no OOB
    CHUNK_BODY(p, e8s, e9s)
  }
#undef CHUNK_BODY

  for (int d = 32; d > 0; d >>= 1) ssum += __shfl_xor(ssum, d, 64);

  // ---- dump G to LDS in bf16 (6.5 KB/wave) ----
#pragma unroll
  for (int v = 0; v < 16; ++v) {
    int rm = (v & 3) + (sh << 2) + ((v >> 2) << 3); // C/D row; col = m
    gb[(rm)      * GB_STRIDE + m] = f2bf(g0[v]);
    gb[(32 + rm) * GB_STRIDE + m] = f2bf(g1[v]);
    gb[(64 + rm) * GB_STRIDE + m] = f2bf(g2[v]);
  }

  // ---- diagonal-band sums: lane handles lag k = lane+1 ----
  int k = lane + 1;
  int s2 = k & 31, q = k >> 5;
  float ck = 0.f;
#pragma unroll 4
  for (int mm = 0; mm < 32; ++mm) {
    int ms = mm + s2;
    int dd = q + (ms >> 5);
    ck += bf2f(gb[(dd * 32 + mm) * GB_STRIDE + (ms & 31)]);
  }
  float c0 = 0.f;
#pragma unroll 4
  for (int mm = 0; mm < 32; ++mm) c0 += bf2f(gb[mm * GB_STRIDE + mm]); // broadcast

  // ---- centering correction: prefix (P_k) / suffix (Q_k) scans over lanes ----
  float P = X[(size_t)row * T_LEN + lane];
  float Q = X[(size_t)row * T_LEN + (T_LEN - 1 - lane)];
  for (int d = 1; d < 64; d <<= 1) {
    float tp = __shfl_up(P, (unsigned)d, 64);
    float tq = __shfl_up(Q, (unsigned)d, 64);
    if (lane >= d) { P += tp; Q += tq; }
  }
  float mu = ssum * (1.0f / (float)T_LEN);
  float Ck = ck - mu * (2.f * ssum - P - Q) + (float)(T_LEN - k) * mu * mu;
  float C0 = c0 - mu * 2.f * ssum + (float)T_LEN * mu * mu;
  out[(size_t)row * 64 + lane] = Ck / C0;
}

extern "C" void kernel_launch(void* const* d_in, const int* in_sizes, int n_in,
                              void* d_out, int out_size, void* d_ws, size_t ws_size,
                              hipStream_t stream) {
  const float* X = (const float*)d_in[0];
  float* out = (float*)d_out;
  int nrows = in_sizes[0] / T_LEN;  // 4096
  dim3 grid((nrows + WPB - 1) / WPB);
  // TIMING EXPERIMENT: 3 idempotent launches; dur_us = overhead + 3*X.
  autocorr_kernel<<<grid, dim3(WPB * 64), 0, stream>>>(X, out, nrows);
  autocorr_kernel<<<grid, dim3(WPB * 64), 0, stream>>>(X, out, nrows);
  autocorr_kernel<<<grid, dim3(WPB * 64), 0, stream>>>(X, out, nrows);
}

// Round 5
// 189.133 us; speedup vs baseline: 1.2486x; 1.2486x over previous
//
#include <hip/hip_runtime.h>

// Batched autocorrelation, X:[4096,8192] f32 -> out:[4096,64] f32.
// Per-row correlation as bf16 MFMA Gram matrices:
//   X_i[m] = x[32 i + m];  G_d[m][n] = sum_i X_i[m] * X_{i+d}[n], d=0..2
//   R_{32q+s} = sum_{m+s<32} G_q[m][m+s] + sum_{m+s>=32} G_{q+1}[m][m+s-32]
// Centering folded in algebraically (fp32):
//   C_k = R_k - mu*(2S - P_k - Q_k) + (T-k) mu^2 ;  out = C_k / C_0
//
// FINAL (== R3, single launch; R4's 3x-launch experiment reverted).
// R4 measurement: kernel X ~= 24.0 us (dur = 164 us harness overhead + X).
// 134.2 MB compulsory HBM read / 24 us = 5.6 TB/s = 89% of the 6.3 TB/s
// achievable-copy ceiling (~9.1 B/cyc/CU vs ~10 ceiling). The 512 MiB
// ws-poison before each timed launch sweeps L3, so reads are true HBM.
// => memory-roofline-bound; remaining kernel headroom ~2.7 us (1.4% of dur).
//
// Design: one wave per row, no barriers, no LDS staging. A-fragment elements
// load straight from global (e_j = x[512c + 256s + 32j + m]; per j each
// 32-lane half reads one contiguous 128 B line). Convert+pack bf16 in-register;
// B1 via funnel shift, B2 via register rename. LDS = 6.5 KB/wave bf16 G-dump
// for the diagonal-band reduction. 256 thr/block, 4 blocks/CU, 16 waves/CU.

typedef __bf16 bf16x8 __attribute__((ext_vector_type(8)));
typedef float f32x16 __attribute__((ext_vector_type(16)));
typedef unsigned int uint32;

#define T_LEN 8192
#define WPB 4                       // waves (rows) per block
#define GB_STRIDE 34                // shorts per G row (+2 pad)
#define GB_SHORTS (96 * GB_STRIDE)  // 3 matrices x 32 rows = 6528 B / wave

__device__ __forceinline__ uint32 pack2bf(float a, float b) { // (lo=a, hi=b) RNE
  uint32 ua = __builtin_bit_cast(uint32, a);
  uint32 ub = __builtin_bit_cast(uint32, b);
  ua += 0x7fffu + ((ua >> 16) & 1u);
  ub += 0x7fffu + ((ub >> 16) & 1u);
  return (ua >> 16) | (ub & 0xffff0000u);
}
__device__ __forceinline__ short f2bf(float f) {
  uint32 u = __builtin_bit_cast(uint32, f);
  return (short)((u + 0x7fffu + ((u >> 16) & 1u)) >> 16);
}
__device__ __forceinline__ float bf2f(short h) {
  uint32 u = ((uint32)(unsigned short)h) << 16;
  return __builtin_bit_cast(float, u);
}

__global__ __launch_bounds__(WPB * 64, 4)
void autocorr_kernel(const float* __restrict__ X, float* __restrict__ out, int nrows) {
  __shared__ short gb_all[WPB * GB_SHORTS];
  const int wave = threadIdx.x >> 6;
  const int lane = threadIdx.x & 63;
  const int row = blockIdx.x * WPB + wave;
  if (row >= nrows) return;               // no barriers anywhere: waves independent
  short* gb = gb_all + wave * GB_SHORTS;

  const int m = lane & 31;                // A-role row m / B-role col n
  const int sh = lane >> 5;               // K-half s
  const float* __restrict__ base = X + (size_t)row * T_LEN + (sh << 8) + m;

  f32x16 g0 = {}, g1 = {}, g2 = {};
  float ssum = 0.f;

#define CHUNK_BODY(PP, E8, E9)                                                  \
  {                                                                             \
    float e0 = (PP)[0],   e1 = (PP)[32],  e2 = (PP)[64],  e3 = (PP)[96];        \
    float e4 = (PP)[128], e5 = (PP)[160], e6 = (PP)[192], e7 = (PP)[224];       \
    float e8 = (E8), e9 = (E9);                                                 \
    ssum += ((e0 + e1) + (e2 + e3)) + ((e4 + e5) + (e6 + e7));                  \
    uint32 u0 = pack2bf(e0, e1), u1 = pack2bf(e2, e3), u2 = pack2bf(e4, e5);    \
    uint32 u3 = pack2bf(e6, e7), u4 = pack2bf(e8, e9);                          \
    int4 a4 = make_int4((int)u0, (int)u1, (int)u2, (int)u3);                    \
    int4 b1;                                                                    \
    b1.x = (int)((u0 >> 16) | (u1 << 16));                                      \
    b1.y = (int)((u1 >> 16) | (u2 << 16));                                      \
    b1.z = (int)((u2 >> 16) | (u3 << 16));                                      \
    b1.w = (int)((u3 >> 16) | (u4 << 16));                                      \
    int4 b2 = make_int4((int)u1, (int)u2, (int)u3, (int)u4);                    \
    bf16x8 fa = __builtin_bit_cast(bf16x8, a4);                                 \
    bf16x8 f1 = __builtin_bit_cast(bf16x8, b1);                                 \
    bf16x8 f2 = __builtin_bit_cast(bf16x8, b2);                                 \
    g0 = __builtin_amdgcn_mfma_f32_32x32x16_bf16(fa, fa, g0, 0, 0, 0);          \
    g1 = __builtin_amdgcn_mfma_f32_32x32x16_bf16(fa, f1, g1, 0, 0, 0);          \
    g2 = __builtin_amdgcn_mfma_f32_32x32x16_bf16(fa, f2, g2, 0, 0, 0);          \
  }

#pragma unroll 3
  for (int c = 0; c < 15; ++c) {
    const float* p = base + (c << 9);
    CHUNK_BODY(p, p[256], p[288])
  }
  { // last chunk: spill elements for the upper half are past end of row -> 0
    const float* p = base + (15 << 9);
    float e8s = 0.f, e9s = 0.f;
    if (!sh) { e8s = p[256]; e9s = p[288]; }   // exec-masked loads, no OOB
    CHUNK_BODY(p, e8s, e9s)
  }
#undef CHUNK_BODY

  for (int d = 32; d > 0; d >>= 1) ssum += __shfl_xor(ssum, d, 64);

  // ---- dump G to LDS in bf16 (6.5 KB/wave) ----
#pragma unroll
  for (int v = 0; v < 16; ++v) {
    int rm = (v & 3) + (sh << 2) + ((v >> 2) << 3); // C/D row; col = m
    gb[(rm)      * GB_STRIDE + m] = f2bf(g0[v]);
    gb[(32 + rm) * GB_STRIDE + m] = f2bf(g1[v]);
    gb[(64 + rm) * GB_STRIDE + m] = f2bf(g2[v]);
  }

  // ---- diagonal-band sums: lane handles lag k = lane+1 ----
  int k = lane + 1;
  int s2 = k & 31, q = k >> 5;
  float ck = 0.f;
#pragma unroll 4
  for (int mm = 0; mm < 32; ++mm) {
    int ms = mm + s2;
    int dd = q + (ms >> 5);
    ck += bf2f(gb[(dd * 32 + mm) * GB_STRIDE + (ms & 31)]);
  }
  float c0 = 0.f;
#pragma unroll 4
  for (int mm = 0; mm < 32; ++mm) c0 += bf2f(gb[mm * GB_STRIDE + mm]); // broadcast

  // ---- centering correction: prefix (P_k) / suffix (Q_k) scans over lanes ----
  float P = X[(size_t)row * T_LEN + lane];
  float Q = X[(size_t)row * T_LEN + (T_LEN - 1 - lane)];
  for (int d = 1; d < 64; d <<= 1) {
    float tp = __shfl_up(P, (unsigned)d, 64);
    float tq = __shfl_up(Q, (unsigned)d, 64);
    if (lane >= d) { P += tp; Q += tq; }
  }
  float mu = ssum * (1.0f / (float)T_LEN);
  float Ck = ck - mu * (2.f * ssum - P - Q) + (float)(T_LEN - k) * mu * mu;
  float C0 = c0 - mu * 2.f * ssum + (float)T_LEN * mu * mu;
  out[(size_t)row * 64 + lane] = Ck / C0;
}

extern "C" void kernel_launch(void* const* d_in, const int* in_sizes, int n_in,
                              void* d_out, int out_size, void* d_ws, size_t ws_size,
                              hipStream_t stream) {
  const float* X = (const float*)d_in[0];
  float* out = (float*)d_out;
  int nrows = in_sizes[0] / T_LEN;  // 4096
  dim3 grid((nrows + WPB - 1) / WPB);
  autocorr_kernel<<<grid, dim3(WPB * 64), 0, stream>>>(X, out, nrows);
}